// Round 5
// baseline (1600.973 us; speedup 1.0000x reference)
//
#include <hip/hip_runtime.h>
#include <cstddef>

#define BB 32
#define CC 192
#define HH 56
#define WW 56
#define NP 3136          // 56*56
#define NHD 6
#define HD 32
#define AG 49
#define C3 576
#define SCALE 0.17677669529663687f   // 32^-0.5
#define NCHUNK 8         // n-split for agent attention (3136 = 8*392)

#define BCN ((size_t)BB*CC*NP)            // 19,267,584 floats
#define SZ_AG ((size_t)BB*AG*CC)          // 301,056
#define SZ_PB ((size_t)NHD*AG*NP)         // 921,984
#define SZ_PSUM ((size_t)BB*NHD*NCHUNK*AG)   // 75,264
#define SZ_PACC (SZ_PSUM*(size_t)HD)         // 2,408,448
// total ws use: 3*BCN + 2*SZ_AG + 2*SZ_PB + SZ_PSUM + SZ_PACC
//             = 62,732,544 floats = 239.3 MiB (was 358 MB in round 4 -> fault)

// ---------------------------------------------------------------------------
// K0: positional biases. pbT[h][n][a] = bilinear(an_bias)+ah+aw (lane=a reads
// coalesce in K3). qb[h][a][n] = bilinear(na_bias)+ha+wa (lane=n reads in K4).
// jax.image.resize linear == half-pixel-center bilinear with edge clamp.
// ---------------------------------------------------------------------------
__global__ __launch_bounds__(256) void k_bias(
    const float* __restrict__ an, const float* __restrict__ na,
    const float* __restrict__ ahb, const float* __restrict__ awb,
    const float* __restrict__ hab, const float* __restrict__ wab,
    float* __restrict__ pbT, float* __restrict__ qb) {
  int idx = blockIdx.x*256 + threadIdx.x;
  if (idx >= NHD*AG*NP) return;
  int n = idx % NP; int t = idx / NP; int a = t % AG; int h = t / AG;
  int y = n / WW, x = n % WW;
  float fy = (y + 0.5f)*0.125f - 0.5f;
  float fx = (x + 0.5f)*0.125f - 0.5f;
  float fyf = floorf(fy), fxf = floorf(fx);
  int y0 = (int)fyf, x0 = (int)fxf;
  float wy = fy - fyf, wx = fx - fxf;
  int y0c = min(6, max(0, y0)), y1c = min(6, max(0, y0+1));
  int x0c = min(6, max(0, x0)), x1c = min(6, max(0, x0+1));
  const float* p = an + (h*AG + a)*49;
  float b1 = (1.f-wy)*((1.f-wx)*p[y0c*7+x0c] + wx*p[y0c*7+x1c])
           + wy*((1.f-wx)*p[y1c*7+x0c] + wx*p[y1c*7+x1c]);
  b1 += ahb[(h*AG+a)*HH + y] + awb[(h*AG+a)*WW + x];
  pbT[((size_t)h*NP + n)*AG + a] = b1;
  p = na + (h*AG + a)*49;
  float b2 = (1.f-wy)*((1.f-wx)*p[y0c*7+x0c] + wx*p[y0c*7+x1c])
           + wy*((1.f-wx)*p[y1c*7+x0c] + wx*p[y1c*7+x1c]);
  b2 += hab[(h*HH+y)*AG + a] + wab[(h*WW+x)*AG + a];
  qb[((size_t)(h*AG+a))*NP + n] = b2;
}

// ---------------------------------------------------------------------------
// K1: qkv = x^T @ Wqkv + b, LDS-free. Wave-uniform co-strip of 16 (B rows via
// s_load broadcast), per-lane A as coalesced float2 from x (C,N). Microtile
// 2n x 16co, 32 FMA / k-step, zero LDS traffic.
//  co 0..191   -> qT[b][h][n][d]
//  co 192..383 -> kT[b][h][n][d]
//  co 384..575 -> vCN[b][c][n]   (only copy of v; used by K3 s_loads + dwconv)
// ---------------------------------------------------------------------------
__global__ __launch_bounds__(256) void k_qkv(
    const float* __restrict__ x, const float* __restrict__ Wq,
    const float* __restrict__ bq, float* __restrict__ qT,
    float* __restrict__ kT, float* __restrict__ vCN) {
  int b = blockIdx.z;
  int n0 = blockIdx.x * 128;
  int w  = __builtin_amdgcn_readfirstlane((int)(threadIdx.x >> 6));
  int lane = threadIdx.x & 63;
  int strip = blockIdx.y * 64 + w * 16;     // 16 consecutive output columns
  int n = n0 + 2*lane;
  bool act = n < NP;                        // NP even -> n+1 also valid
  int nc = act ? n : 0;
  const float* xb = x + (size_t)b*CC*NP + nc;
  const float* wp = Wq + strip;
  float acc0[16], acc1[16];
#pragma unroll
  for (int j=0;j<16;++j) { acc0[j]=0.f; acc1[j]=0.f; }
  float2 a = *(const float2*)xb;
#pragma unroll 2
  for (int kk=0; kk<CC-1; ++kk) {
    float2 a_n = *(const float2*)(xb + (size_t)(kk+1)*NP);
    const float* wr = wp + (size_t)kk*C3;   // wave-uniform -> s_load
#pragma unroll
    for (int j=0;j<16;++j) {
      float bsv = wr[j];
      acc0[j] += a.x * bsv;
      acc1[j] += a.y * bsv;
    }
    a = a_n;
  }
  {
    const float* wr = wp + (size_t)(CC-1)*C3;
#pragma unroll
    for (int j=0;j<16;++j) {
      float bsv = wr[j];
      acc0[j] += a.x * bsv;
      acc1[j] += a.y * bsv;
    }
  }
  if (!act) return;
  int sec = strip / 192;          // 0=q 1=k 2=v
  int r = strip % 192;
  float o0[16], o1[16];
#pragma unroll
  for (int j=0;j<16;++j) {
    float bb = bq[strip + j];     // uniform s_load
    o0[j] = acc0[j] + bb;
    o1[j] = acc1[j] + bb;
  }
  if (sec < 2) {
    int h = r >> 5;               // head (strip never crosses a head: 16|32)
    int d0 = r & 31;              // 0 or 16
    float* outT = (sec==0 ? qT : kT);
    float* base0 = outT + (((size_t)(b*NHD + h)*NP + n)*HD + d0);
    float* base1 = base0 + HD;    // n+1
#pragma unroll
    for (int g=0; g<4; ++g) {
      *(float4*)(base0 + g*4) = make_float4(o0[g*4],o0[g*4+1],o0[g*4+2],o0[g*4+3]);
      *(float4*)(base1 + g*4) = make_float4(o1[g*4],o1[g*4+1],o1[g*4+2],o1[g*4+3]);
    }
  } else {                        // v -> (C,N) only
#pragma unroll
    for (int j=0;j<16;++j) {
      float* dst = vCN + ((size_t)b*CC + r + j)*NP + n;
      *(float2*)dst = make_float2(o0[j], o1[j]);
    }
  }
}

// ---------------------------------------------------------------------------
// K2: agent pooling: agent[b][a][c] = mean of q over the 8x8 patch of cell a.
// ---------------------------------------------------------------------------
__global__ __launch_bounds__(192) void k_pool(const float* __restrict__ qT,
                                              float* __restrict__ agent) {
  int b = blockIdx.x / AG, a = blockIdx.x % AG;
  int c = threadIdx.x;
  int h = c >> 5, d = c & 31;
  int p1 = a / 7, p2 = a % 7;
  const float* base = qT + ((size_t)(b*NHD + h)*NP)*HD + d;
  float s = 0.f;
#pragma unroll
  for (int fy=0; fy<8; ++fy) {
    int y = p1*8 + fy;
#pragma unroll
    for (int fx=0; fx<8; ++fx) {
      int n = y*WW + p2*8 + fx;
      s += base[(size_t)n*HD];
    }
  }
  agent[((size_t)(b*AG + a))*CC + c] = s * 0.015625f;
}

// ---------------------------------------------------------------------------
// K3: agent attention, lane = a (49 active), single pass (no max-sub: |s|<~2).
// Each wave handles one 392-n chunk; partial (sum_e, sum_e*v) to ws.
// chunk via readfirstlane -> k rows (kT, dwordx4) and v columns (vCN,
// 32 stride-NP dwords with immediate offsets) are wave-uniform s_loads.
// ---------------------------------------------------------------------------
__global__ __launch_bounds__(256) void k_aattn(
    const float* __restrict__ kT, const float* __restrict__ vCN,
    const float* __restrict__ agent, const float* __restrict__ pbT,
    float* __restrict__ psum, float* __restrict__ pacc) {
  int b = blockIdx.z, h = blockIdx.y;
  int lane = threadIdx.x & 63;
  int chunk = __builtin_amdgcn_readfirstlane(
      (int)(blockIdx.x*4) + (int)(threadIdx.x >> 6));   // 0..NCHUNK-1
  bool act = lane < AG;
  int a = act ? lane : 0;
  float ahr[HD];
  const float* ap = agent + ((size_t)(b*AG + a))*CC + h*HD;
#pragma unroll
  for (int d=0; d<HD; d+=4) {
    float4 t4 = *(const float4*)(ap + d);
    ahr[d]=t4.x; ahr[d+1]=t4.y; ahr[d+2]=t4.z; ahr[d+3]=t4.w;
  }
  float acc[HD];
#pragma unroll
  for (int d=0; d<HD; ++d) acc[d]=0.f;
  float sumE = 0.f;
  int n0 = chunk*(NP/NCHUNK), n1 = n0 + (NP/NCHUNK);
  const float* kb  = kT + ((size_t)(b*NHD + h)*NP)*HD;
  const float* vb2 = vCN + ((size_t)b*CC + h*HD)*NP;   // v column base
  const float* pbb = pbT + (size_t)h*NP*AG + a;
  for (int n=n0; n<n1; ++n) {
    const float* kr = kb + (size_t)n*HD;    // wave-uniform address
    float kv[HD];
#pragma unroll
    for (int d=0; d<HD; d+=4) {
      float4 t4 = *(const float4*)(kr + d);
      kv[d]=t4.x; kv[d+1]=t4.y; kv[d+2]=t4.z; kv[d+3]=t4.w;
    }
    float s0=0.f,s1=0.f,s2=0.f,s3=0.f;
#pragma unroll
    for (int d=0; d<HD; d+=4) {
      s0 += ahr[d]*kv[d]; s1 += ahr[d+1]*kv[d+1];
      s2 += ahr[d+2]*kv[d+2]; s3 += ahr[d+3]*kv[d+3];
    }
    float e = __expf(((s0+s1)+(s2+s3))*SCALE + pbb[(size_t)n*AG]);
    if (!act) e = 0.f;
    sumE += e;
    const float* vn = vb2 + n;              // wave-uniform; d*NP = imm offset
#pragma unroll
    for (int d=0; d<HD; ++d) acc[d] += e * vn[(size_t)d*NP];
  }
  if (act) {
    size_t cidx = ((size_t)((b*NHD + h)*NCHUNK) + chunk)*AG + lane;
    psum[cidx] = sumE;
    float* pa = pacc + cidx*HD;
#pragma unroll
    for (int d=0; d<HD; d+=4)
      *(float4*)(pa + d) = make_float4(acc[d],acc[d+1],acc[d+2],acc[d+3]);
  }
}

// K3b: combine partial chunks -> agent_v[b][h][a][d]
__global__ __launch_bounds__(256) void k_comb(
    const float* __restrict__ psum, const float* __restrict__ pacc,
    float* __restrict__ agv) {
  int idx = blockIdx.x*256 + threadIdx.x;
  if (idx >= (int)(BB*NHD*AG*HD)) return;
  int d = idx & (HD-1); int rest = idx >> 5; int a = rest % AG; int bh = rest / AG;
  float se = 0.f, sa = 0.f;
  const float* pp = psum + (size_t)bh*NCHUNK*AG + a;
  const float* pa = pacc + ((size_t)bh*NCHUNK*AG + a)*HD + d;
#pragma unroll
  for (int ch=0; ch<NCHUNK; ++ch) {
    se += pp[(size_t)ch*AG];
    sa += pa[(size_t)ch*AG*HD];
  }
  agv[idx] = sa / se;
}

// ---------------------------------------------------------------------------
// K4: q attention + FUSED depthwise 3x3 conv. lane = n (coalesced); agent /
// agent_v rows wave-uniform -> s_loads. After softmax-normalize, adds the
// dwconv of vCN (coalesced per channel/tap, L1 absorbs 9x tap reuse) and
// writes t (C,N) exactly once.
// ---------------------------------------------------------------------------
__global__ __launch_bounds__(256) void k_qattn(
    const float* __restrict__ qT, const float* __restrict__ agent,
    const float* __restrict__ agv, const float* __restrict__ qb,
    const float* __restrict__ v, const float* __restrict__ dwcw,
    const float* __restrict__ dwcb, float* __restrict__ t) {
  int b = blockIdx.z, h = blockIdx.y;
  int n = blockIdx.x*256 + threadIdx.x;
  bool act = n < NP;
  int nc = act ? n : 0;
  float qreg[HD];
  const float* qp = qT + ((size_t)(b*NHD + h)*NP + nc)*HD;
#pragma unroll
  for (int d=0; d<HD; d+=4) {
    float4 tv = *(const float4*)(qp+d);
    qreg[d]=tv.x; qreg[d+1]=tv.y; qreg[d+2]=tv.z; qreg[d+3]=tv.w;
  }
  float acc[HD];
#pragma unroll
  for (int d=0; d<HD; ++d) acc[d]=0.f;
  float sumE=0.f;
  const float* agb = agent + (size_t)b*AG*CC + h*HD;
  const float* avb = agv + (size_t)(b*NHD + h)*AG*HD;
  const float* qbb = qb + (size_t)h*AG*NP + nc;
  for (int a=0; a<AG; ++a) {
    const float* ar = agb + (size_t)a*CC;   // wave-uniform
    float s0=0.f,s1=0.f,s2=0.f,s3=0.f;
#pragma unroll
    for (int d=0; d<HD; d+=4) {
      s0 += qreg[d]*ar[d]; s1 += qreg[d+1]*ar[d+1];
      s2 += qreg[d+2]*ar[d+2]; s3 += qreg[d+3]*ar[d+3];
    }
    float e = __expf(((s0+s1)+(s2+s3))*SCALE + qbb[(size_t)a*NP]);
    sumE += e;
    const float* vr = avb + a*HD;           // wave-uniform
#pragma unroll
    for (int d=0; d<HD; ++d) acc[d] += e*vr[d];
  }
  float inv = 1.0f / sumE;
  int y = nc / WW, x = nc % WW;
  const float* vbase = v + (size_t)b*CC*NP;
  float* tb = t + ((size_t)b*CC + h*HD)*NP + nc;
#pragma unroll 4
  for (int d=0; d<HD; ++d) {
    int c = h*HD + d;
    const float* wp9 = dwcw + c*9;          // wave-uniform
    const float* vp = vbase + (size_t)c*NP;
    float s = dwcb[c];
#pragma unroll
    for (int dy=-1; dy<=1; ++dy) {
      int yy = y+dy; if (yy < 0 || yy >= HH) continue;
#pragma unroll
      for (int dx=-1; dx<=1; ++dx) {
        int xx = x+dx; if (xx < 0 || xx >= WW) continue;
        s += wp9[(dy+1)*3 + (dx+1)] * vp[yy*WW + xx];
      }
    }
    if (act) tb[(size_t)d*NP] = acc[d]*inv + s;
  }
}

// ---------------------------------------------------------------------------
// K6: out = t^T @ proj_w + proj_b, LDS-free scalar-B GEMM (same scheme as K1),
// written as (B,C,N) == (b,c,h,w). Coalesced float2 stores per co.
// ---------------------------------------------------------------------------
__global__ __launch_bounds__(256) void k_proj(
    const float* __restrict__ t, const float* __restrict__ Wp,
    const float* __restrict__ bp, float* __restrict__ out) {
  int b = blockIdx.z;
  int n0 = blockIdx.x * 128;
  int w  = __builtin_amdgcn_readfirstlane((int)(threadIdx.x >> 6));
  int lane = threadIdx.x & 63;
  int strip = blockIdx.y * 64 + w * 16;     // co in [0,192)
  int n = n0 + 2*lane;
  bool act = n < NP;
  int nc = act ? n : 0;
  const float* tb = t + (size_t)b*CC*NP + nc;
  const float* wp = Wp + strip;
  float acc0[16], acc1[16];
#pragma unroll
  for (int j=0;j<16;++j) { acc0[j]=0.f; acc1[j]=0.f; }
  float2 a = *(const float2*)tb;
#pragma unroll 2
  for (int kk=0; kk<CC-1; ++kk) {
    float2 a_n = *(const float2*)(tb + (size_t)(kk+1)*NP);
    const float* wr = wp + (size_t)kk*CC;   // wave-uniform -> s_load
#pragma unroll
    for (int j=0;j<16;++j) {
      float bsv = wr[j];
      acc0[j] += a.x * bsv;
      acc1[j] += a.y * bsv;
    }
    a = a_n;
  }
  {
    const float* wr = wp + (size_t)(CC-1)*CC;
#pragma unroll
    for (int j=0;j<16;++j) {
      float bsv = wr[j];
      acc0[j] += a.x * bsv;
      acc1[j] += a.y * bsv;
    }
  }
  if (!act) return;
#pragma unroll
  for (int j=0;j<16;++j) {
    float bb = bp[strip + j];
    float* dst = out + ((size_t)b*CC + strip + j)*NP + n;
    *(float2*)dst = make_float2(acc0[j] + bb, acc1[j] + bb);
  }
}

// ---------------------------------------------------------------------------
extern "C" void kernel_launch(void* const* d_in, const int* in_sizes, int n_in,
                              void* d_out, int out_size, void* d_ws, size_t ws_size,
                              hipStream_t stream) {
  const float* x    = (const float*)d_in[0];
  const float* Wqkv = (const float*)d_in[1];
  const float* bqkv = (const float*)d_in[2];
  const float* projw= (const float*)d_in[3];
  const float* projb= (const float*)d_in[4];
  const float* dwcw = (const float*)d_in[5];
  const float* dwcb = (const float*)d_in[6];
  const float* an   = (const float*)d_in[7];
  const float* na   = (const float*)d_in[8];
  const float* ahb  = (const float*)d_in[9];
  const float* awb  = (const float*)d_in[10];
  const float* hab  = (const float*)d_in[11];
  const float* wab  = (const float*)d_in[12];
  float* out = (float*)d_out;

  float* w0   = (float*)d_ws;
  float* qT   = w0;                  // [B][NH][N][HD]
  float* kT   = qT + BCN;            // [B][NH][N][HD]  (reused as t after K3)
  float* vCN  = kT + BCN;            // [B][C][N]
  float* agent= vCN + BCN;           // [B][A][C]
  float* agv  = agent + SZ_AG;       // [B][NH][A][HD]
  float* pbT  = agv + SZ_AG;         // [NH][N][A]
  float* qb   = pbT + SZ_PB;         // [NH][A][N]
  float* psum = qb + SZ_PB;
  float* pacc = psum + SZ_PSUM;
  float* t    = kT;                  // alias: kT dead after k_aattn

  k_bias<<<dim3(3602), dim3(256), 0, stream>>>(an, na, ahb, awb, hab, wab, pbT, qb);
  k_qkv<<<dim3(25, 9, BB), dim3(256), 0, stream>>>(x, Wqkv, bqkv, qT, kT, vCN);
  k_pool<<<dim3(BB*AG), dim3(192), 0, stream>>>(qT, agent);
  k_aattn<<<dim3(NCHUNK/4, NHD, BB), dim3(256), 0, stream>>>(kT, vCN, agent, pbT, psum, pacc);
  k_comb<<<dim3(1176), dim3(256), 0, stream>>>(psum, pacc, agv);
  k_qattn<<<dim3(13, NHD, BB), dim3(256), 0, stream>>>(qT, agent, agv, qb, vCN, dwcw, dwcb, t);
  k_proj<<<dim3(25, 3, BB), dim3(256), 0, stream>>>(t, projw, projb, out);
}

// Round 8
// 1253.192 us; speedup vs baseline: 1.2775x; 1.2775x over previous
//
#include <hip/hip_runtime.h>
#include <cstddef>

#define BB 32
#define CC 192
#define HH 56
#define WW 56
#define NP 3136          // 56*56
#define NHD 6
#define HD 32
#define AG 49
#define C3 576
#define SCALE 0.17677669529663687f   // 32^-0.5
#define NCHUNK 4         // grid n-chunks for agent attention (3136 = 4*784)
#define ATILE 112        // n-tile inside k_aattn (784 = 7*112)
#define EP 116           // padded LDS row (116%4==0 -> b128-aligned)

#define BCN ((size_t)BB*CC*NP)            // 19,267,584 floats
#define SZ_AG ((size_t)BB*AG*CC)          // 301,056
#define SZ_PB ((size_t)NHD*AG*NP)         // 921,984
#define SZ_PSUM ((size_t)BB*NHD*NCHUNK*AG)   // 37,632
#define SZ_PACC (SZ_PSUM*(size_t)HD)         // 1,204,224
// total ws: 3*BCN + 2*SZ_AG + 2*SZ_PB + SZ_PSUM + SZ_PACC = 61,490,688 floats
//         = 234.6 MiB  (round-5 used 239.3 MiB and passed)

// ---------------------------------------------------------------------------
// K0: positional biases. pbT[h][a][n] = bilinear(an_bias)+ah+aw (lane=n reads
// coalesce in K3 phase A). qb[h][a][n] = bilinear(na_bias)+ha+wa (K4).
// ---------------------------------------------------------------------------
__global__ __launch_bounds__(256) void k_bias(
    const float* __restrict__ an, const float* __restrict__ na,
    const float* __restrict__ ahb, const float* __restrict__ awb,
    const float* __restrict__ hab, const float* __restrict__ wab,
    float* __restrict__ pbT, float* __restrict__ qb) {
  int idx = blockIdx.x*256 + threadIdx.x;
  if (idx >= NHD*AG*NP) return;
  int n = idx % NP; int t = idx / NP; int a = t % AG; int h = t / AG;
  int y = n / WW, x = n % WW;
  float fy = (y + 0.5f)*0.125f - 0.5f;
  float fx = (x + 0.5f)*0.125f - 0.5f;
  float fyf = floorf(fy), fxf = floorf(fx);
  int y0 = (int)fyf, x0 = (int)fxf;
  float wy = fy - fyf, wx = fx - fxf;
  int y0c = min(6, max(0, y0)), y1c = min(6, max(0, y0+1));
  int x0c = min(6, max(0, x0)), x1c = min(6, max(0, x0+1));
  const float* p = an + (h*AG + a)*49;
  float b1 = (1.f-wy)*((1.f-wx)*p[y0c*7+x0c] + wx*p[y0c*7+x1c])
           + wy*((1.f-wx)*p[y1c*7+x0c] + wx*p[y1c*7+x1c]);
  b1 += ahb[(h*AG+a)*HH + y] + awb[(h*AG+a)*WW + x];
  pbT[((size_t)h*AG + a)*NP + n] = b1;          // [h][a][n]
  p = na + (h*AG + a)*49;
  float b2 = (1.f-wy)*((1.f-wx)*p[y0c*7+x0c] + wx*p[y0c*7+x1c])
           + wy*((1.f-wx)*p[y1c*7+x0c] + wx*p[y1c*7+x1c]);
  b2 += hab[(h*HH+y)*AG + a] + wab[(h*WW+x)*AG + a];
  qb[((size_t)(h*AG+a))*NP + n] = b2;
}

// ---------------------------------------------------------------------------
// K1: qkv = x^T @ Wqkv + b, LDS-free (unchanged from round 5, validated).
// ---------------------------------------------------------------------------
__global__ __launch_bounds__(256) void k_qkv(
    const float* __restrict__ x, const float* __restrict__ Wq,
    const float* __restrict__ bq, float* __restrict__ qT,
    float* __restrict__ kT, float* __restrict__ vCN) {
  int b = blockIdx.z;
  int n0 = blockIdx.x * 128;
  int w  = __builtin_amdgcn_readfirstlane((int)(threadIdx.x >> 6));
  int lane = threadIdx.x & 63;
  int strip = blockIdx.y * 64 + w * 16;
  int n = n0 + 2*lane;
  bool act = n < NP;
  int nc = act ? n : 0;
  const float* xb = x + (size_t)b*CC*NP + nc;
  const float* wp = Wq + strip;
  float acc0[16], acc1[16];
#pragma unroll
  for (int j=0;j<16;++j) { acc0[j]=0.f; acc1[j]=0.f; }
  float2 a = *(const float2*)xb;
#pragma unroll 2
  for (int kk=0; kk<CC-1; ++kk) {
    float2 a_n = *(const float2*)(xb + (size_t)(kk+1)*NP);
    const float* wr = wp + (size_t)kk*C3;   // wave-uniform -> s_load
#pragma unroll
    for (int j=0;j<16;++j) {
      float bsv = wr[j];
      acc0[j] += a.x * bsv;
      acc1[j] += a.y * bsv;
    }
    a = a_n;
  }
  {
    const float* wr = wp + (size_t)(CC-1)*C3;
#pragma unroll
    for (int j=0;j<16;++j) {
      float bsv = wr[j];
      acc0[j] += a.x * bsv;
      acc1[j] += a.y * bsv;
    }
  }
  if (!act) return;
  int sec = strip / 192;          // 0=q 1=k 2=v
  int r = strip % 192;
  float o0[16], o1[16];
#pragma unroll
  for (int j=0;j<16;++j) {
    float bb = bq[strip + j];
    o0[j] = acc0[j] + bb;
    o1[j] = acc1[j] + bb;
  }
  if (sec < 2) {
    int h = r >> 5;
    int d0 = r & 31;
    float* outT = (sec==0 ? qT : kT);
    float* base0 = outT + (((size_t)(b*NHD + h)*NP + n)*HD + d0);
    float* base1 = base0 + HD;
#pragma unroll
    for (int g=0; g<4; ++g) {
      *(float4*)(base0 + g*4) = make_float4(o0[g*4],o0[g*4+1],o0[g*4+2],o0[g*4+3]);
      *(float4*)(base1 + g*4) = make_float4(o1[g*4],o1[g*4+1],o1[g*4+2],o1[g*4+3]);
    }
  } else {
#pragma unroll
    for (int j=0;j<16;++j) {
      float* dst = vCN + ((size_t)b*CC + r + j)*NP + n;
      *(float2*)dst = make_float2(o0[j], o1[j]);
    }
  }
}

// ---------------------------------------------------------------------------
// K2: agent pooling (unchanged).
// ---------------------------------------------------------------------------
__global__ __launch_bounds__(192) void k_pool(const float* __restrict__ qT,
                                              float* __restrict__ agent) {
  int b = blockIdx.x / AG, a = blockIdx.x % AG;
  int c = threadIdx.x;
  int h = c >> 5, d = c & 31;
  int p1 = a / 7, p2 = a % 7;
  const float* base = qT + ((size_t)(b*NHD + h)*NP)*HD + d;
  float s = 0.f;
#pragma unroll
  for (int fy=0; fy<8; ++fy) {
    int y = p1*8 + fy;
#pragma unroll
    for (int fx=0; fx<8; ++fx) {
      int n = y*WW + p2*8 + fx;
      s += base[(size_t)n*HD];
    }
  }
  agent[((size_t)(b*AG + a))*CC + c] = s * 0.015625f;
}

// ---------------------------------------------------------------------------
// K3: agent attention, two-phase LDS-tiled.
// Block = (chunk, h, b); 784 n per block, 7 tiles of 112.
// Phase A: lane=n. k row in VGPRs (coalesced), agent rows via s_load
//   (wave-uniform a-half), pbT[h][a][n] coalesced. e[a][n] -> LDS.
// Phase B: 49x32 PV-GEMM from LDS. lane=(d8,a8); thread tile 7a x 4d with
//   STRIDED d (d = d8 + 8*dd): 8 lanes at fixed dd read 8 consecutive rows
//   (row stride EP=116 -> bank starts 20*d8 mod 32, all 8 distinct quads)
//   -> zero bank conflicts on both e and v reads.
// Block-end: acc reduced across waves via LDS overlay; psum by threads<49.
// ---------------------------------------------------------------------------
__global__ __launch_bounds__(256) void k_aattn(
    const float* __restrict__ kT, const float* __restrict__ vCN,
    const float* __restrict__ agent, const float* __restrict__ pbT,
    float* __restrict__ psum, float* __restrict__ pacc) {
  __shared__ float4 smem4[2552];               // 10208 floats = 40.8 KB
  float* e_lds = (float*)smem4;                // [56][EP] (rows 49..55 unused)
  float* v_lds = e_lds + 56*EP;                // [32][EP]
  int b = blockIdx.z, h = blockIdx.y, chunk = blockIdx.x;
  int bh = b*NHD + h;
  int tid = threadIdx.x;
  int w = __builtin_amdgcn_readfirstlane(tid >> 6);
  int lane = tid & 63;
  int gn0 = chunk * (NP/NCHUNK);               // 784*chunk
  // phase-A role (wave-uniform a-half)
  int half = w >> 1;                           // 0: a 0..24, 1: a 25..48
  int a0 = half*25, na = half ? 24 : 25;
  int n_loc_a = (w & 1)*64 + lane;             // 0..127, active if <ATILE
  // phase-B role
  int a8 = lane & 7, d8 = lane >> 3;
  float acc[7][4];
#pragma unroll
  for (int j=0;j<7;++j)
#pragma unroll
    for (int dd=0;dd<4;++dd) acc[j][dd]=0.f;
  float se_acc = 0.f;
  const float* kb = kT + (size_t)bh*NP*HD;
  const float* vb = vCN + ((size_t)b*CC + h*HD)*NP;
  for (int tile=0; tile<7; ++tile) {
    int t0 = gn0 + tile*ATILE;
    // ---- stage v tile: v_lds[d][c] over 32 x 112 ----
#pragma unroll
    for (int jj=0; jj<14; ++jj) {
      int f = tid + 256*jj;                    // 0..3583
      int d = f / ATILE, c = f % ATILE;
      v_lds[d*EP + c] = vb[(size_t)d*NP + t0 + c];
    }
    // ---- phase A: scores -> e_lds ----
    if (n_loc_a < ATILE) {
      int n = t0 + n_loc_a;
      const float* kr = kb + (size_t)n*HD;
      float kv[HD];
#pragma unroll
      for (int d=0; d<HD; d+=4) {
        float4 t4 = *(const float4*)(kr + d);
        kv[d]=t4.x; kv[d+1]=t4.y; kv[d+2]=t4.z; kv[d+3]=t4.w;
      }
      for (int ai=0; ai<na; ++ai) {
        int a = a0 + ai;
        const float* ag = agent + ((size_t)(b*AG + a))*CC + h*HD; // uniform
        float s0=0.f,s1=0.f,s2=0.f,s3=0.f;
#pragma unroll
        for (int d=0; d<HD; d+=4) {
          s0 += ag[d]*kv[d];   s1 += ag[d+1]*kv[d+1];
          s2 += ag[d+2]*kv[d+2]; s3 += ag[d+3]*kv[d+3];
        }
        float pb = pbT[((size_t)h*AG + a)*NP + n];
        e_lds[a*EP + n_loc_a] = __expf(((s0+s1)+(s2+s3))*SCALE + pb);
      }
    }
    __syncthreads();
    // ---- phase B: acc += e @ v over this tile (d strided: d = d8 + 8*dd) ----
#pragma unroll
    for (int i=0; i<7; ++i) {
      int nq = (i*4 + w)*4;                    // quad col
      float4 v0 = *(const float4*)&v_lds[(d8 +  0)*EP + nq];
      float4 v1 = *(const float4*)&v_lds[(d8 +  8)*EP + nq];
      float4 v2 = *(const float4*)&v_lds[(d8 + 16)*EP + nq];
      float4 v3 = *(const float4*)&v_lds[(d8 + 24)*EP + nq];
#pragma unroll
      for (int j=0;j<7;++j) {
        float4 e4 = *(const float4*)&e_lds[(a8+8*j)*EP + nq];
        acc[j][0] += e4.x*v0.x + e4.y*v0.y + e4.z*v0.z + e4.w*v0.w;
        acc[j][1] += e4.x*v1.x + e4.y*v1.y + e4.z*v1.z + e4.w*v1.w;
        acc[j][2] += e4.x*v2.x + e4.y*v2.y + e4.z*v2.z + e4.w*v2.w;
        acc[j][3] += e4.x*v3.x + e4.y*v3.y + e4.z*v3.z + e4.w*v3.w;
      }
    }
    // ---- row sums for softmax denom (threads 0..48) ----
    if (tid < AG) {
      const float* er = e_lds + tid*EP;
#pragma unroll
      for (int i=0; i<ATILE/4; ++i) {
        float4 ee = *(const float4*)(er + i*4);
        se_acc += ee.x + ee.y + ee.z + ee.w;
      }
    }
    __syncthreads();
  }
  // ---- reduce acc across the 4 waves via LDS overlay ----
  float4* red = (float4*)smem4;                // 256*7 = 1792 float4 = 28 KB
#pragma unroll
  for (int j=0;j<7;++j)
    red[tid*7 + j] = make_float4(acc[j][0],acc[j][1],acc[j][2],acc[j][3]);
  __syncthreads();
  if (tid < 64) {
#pragma unroll
    for (int j=0;j<7;++j) {
      float4 r0 = red[tid*7 + j];
      float4 r1 = red[(tid+64)*7 + j];
      float4 r2 = red[(tid+128)*7 + j];
      float4 r3 = red[(tid+192)*7 + j];
      int a = (tid & 7) + 8*j;
      if (a < AG) {
        int dbase = tid >> 3;                  // d = dbase + 8*dd (strided)
        float* pp = &pacc[(((size_t)bh*NCHUNK + chunk)*AG + a)*HD];
        pp[dbase +  0] = r0.x + r1.x + r2.x + r3.x;
        pp[dbase +  8] = r0.y + r1.y + r2.y + r3.y;
        pp[dbase + 16] = r0.z + r1.z + r2.z + r3.z;
        pp[dbase + 24] = r0.w + r1.w + r2.w + r3.w;
      }
    }
  }
  if (tid < AG)
    psum[((size_t)bh*NCHUNK + chunk)*AG + tid] = se_acc;
}

// K3b: combine partial chunks -> agent_v[b][h][a][d]
__global__ __launch_bounds__(256) void k_comb(
    const float* __restrict__ psum, const float* __restrict__ pacc,
    float* __restrict__ agv) {
  int idx = blockIdx.x*256 + threadIdx.x;
  if (idx >= (int)(BB*NHD*AG*HD)) return;
  int d = idx & (HD-1); int rest = idx >> 5; int a = rest % AG; int bh = rest / AG;
  float se = 0.f, sa = 0.f;
  const float* pp = psum + (size_t)bh*NCHUNK*AG + a;
  const float* pa = pacc + ((size_t)bh*NCHUNK*AG + a)*HD + d;
#pragma unroll
  for (int ch=0; ch<NCHUNK; ++ch) {
    se += pp[(size_t)ch*AG];
    sa += pa[(size_t)ch*AG*HD];
  }
  agv[idx] = sa / se;
}

// ---------------------------------------------------------------------------
// K4: q attention + fused depthwise 3x3 conv (unchanged, validated).
// ---------------------------------------------------------------------------
__global__ __launch_bounds__(256) void k_qattn(
    const float* __restrict__ qT, const float* __restrict__ agent,
    const float* __restrict__ agv, const float* __restrict__ qb,
    const float* __restrict__ v, const float* __restrict__ dwcw,
    const float* __restrict__ dwcb, float* __restrict__ t) {
  int b = blockIdx.z, h = blockIdx.y;
  int n = blockIdx.x*256 + threadIdx.x;
  bool act = n < NP;
  int nc = act ? n : 0;
  float qreg[HD];
  const float* qp = qT + ((size_t)(b*NHD + h)*NP + nc)*HD;
#pragma unroll
  for (int d=0; d<HD; d+=4) {
    float4 tv = *(const float4*)(qp+d);
    qreg[d]=tv.x; qreg[d+1]=tv.y; qreg[d+2]=tv.z; qreg[d+3]=tv.w;
  }
  float acc[HD];
#pragma unroll
  for (int d=0; d<HD; ++d) acc[d]=0.f;
  float sumE=0.f;
  const float* agb = agent + (size_t)b*AG*CC + h*HD;
  const float* avb = agv + (size_t)(b*NHD + h)*AG*HD;
  const float* qbb = qb + (size_t)h*AG*NP + nc;
  for (int a=0; a<AG; ++a) {
    const float* ar = agb + (size_t)a*CC;   // wave-uniform
    float s0=0.f,s1=0.f,s2=0.f,s3=0.f;
#pragma unroll
    for (int d=0; d<HD; d+=4) {
      s0 += qreg[d]*ar[d]; s1 += qreg[d+1]*ar[d+1];
      s2 += qreg[d+2]*ar[d+2]; s3 += qreg[d+3]*ar[d+3];
    }
    float e = __expf(((s0+s1)+(s2+s3))*SCALE + qbb[(size_t)a*NP]);
    sumE += e;
    const float* vr = avb + a*HD;           // wave-uniform
#pragma unroll
    for (int d=0; d<HD; ++d) acc[d] += e*vr[d];
  }
  float inv = 1.0f / sumE;
  int y = nc / WW, x = nc % WW;
  const float* vbase = v + (size_t)b*CC*NP;
  float* tb = t + ((size_t)b*CC + h*HD)*NP + nc;
#pragma unroll 4
  for (int d=0; d<HD; ++d) {
    int c = h*HD + d;
    const float* wp9 = dwcw + c*9;          // wave-uniform
    const float* vp = vbase + (size_t)c*NP;
    float s = dwcb[c];
#pragma unroll
    for (int dy=-1; dy<=1; ++dy) {
      int yy = y+dy; if (yy < 0 || yy >= HH) continue;
#pragma unroll
      for (int dx=-1; dx<=1; ++dx) {
        int xx = x+dx; if (xx < 0 || xx >= WW) continue;
        s += wp9[(dy+1)*3 + (dx+1)] * vp[yy*WW + xx];
      }
    }
    if (act) tb[(size_t)d*NP] = acc[d]*inv + s;
  }
}

// ---------------------------------------------------------------------------
// K6: out = t^T @ proj_w + proj_b (unchanged, validated).
// ---------------------------------------------------------------------------
__global__ __launch_bounds__(256) void k_proj(
    const float* __restrict__ t, const float* __restrict__ Wp,
    const float* __restrict__ bp, float* __restrict__ out) {
  int b = blockIdx.z;
  int n0 = blockIdx.x * 128;
  int w  = __builtin_amdgcn_readfirstlane((int)(threadIdx.x >> 6));
  int lane = threadIdx.x & 63;
  int strip = blockIdx.y * 64 + w * 16;
  int n = n0 + 2*lane;
  bool act = n < NP;
  int nc = act ? n : 0;
  const float* tb = t + (size_t)b*CC*NP + nc;
  const float* wp = Wp + strip;
  float acc0[16], acc1[16];
#pragma unroll
  for (int j=0;j<16;++j) { acc0[j]=0.f; acc1[j]=0.f; }
  float2 a = *(const float2*)tb;
#pragma unroll 2
  for (int kk=0; kk<CC-1; ++kk) {
    float2 a_n = *(const float2*)(tb + (size_t)(kk+1)*NP);
    const float* wr = wp + (size_t)kk*CC;   // wave-uniform -> s_load
#pragma unroll
    for (int j=0;j<16;++j) {
      float bsv = wr[j];
      acc0[j] += a.x * bsv;
      acc1[j] += a.y * bsv;
    }
    a = a_n;
  }
  {
    const float* wr = wp + (size_t)(CC-1)*CC;
#pragma unroll
    for (int j=0;j<16;++j) {
      float bsv = wr[j];
      acc0[j] += a.x * bsv;
      acc1[j] += a.y * bsv;
    }
  }
  if (!act) return;
#pragma unroll
  for (int j=0;j<16;++j) {
    float bb = bp[strip + j];
    float* dst = out + ((size_t)b*CC + strip + j)*NP + n;
    *(float2*)dst = make_float2(acc0[j] + bb, acc1[j] + bb);
  }
}

// ---------------------------------------------------------------------------
extern "C" void kernel_launch(void* const* d_in, const int* in_sizes, int n_in,
                              void* d_out, int out_size, void* d_ws, size_t ws_size,
                              hipStream_t stream) {
  const float* x    = (const float*)d_in[0];
  const float* Wqkv = (const float*)d_in[1];
  const float* bqkv = (const float*)d_in[2];
  const float* projw= (const float*)d_in[3];
  const float* projb= (const float*)d_in[4];
  const float* dwcw = (const float*)d_in[5];
  const float* dwcb = (const float*)d_in[6];
  const float* an   = (const float*)d_in[7];
  const float* na   = (const float*)d_in[8];
  const float* ahb  = (const float*)d_in[9];
  const float* awb  = (const float*)d_in[10];
  const float* hab  = (const float*)d_in[11];
  const float* wab  = (const float*)d_in[12];
  float* out = (float*)d_out;

  float* w0   = (float*)d_ws;
  float* qT   = w0;                  // [B][NH][N][HD]
  float* kT   = qT + BCN;            // [B][NH][N][HD]  (reused as t after K3)
  float* vCN  = kT + BCN;            // [B][C][N]
  float* agent= vCN + BCN;           // [B][A][C]
  float* agv  = agent + SZ_AG;       // [B][NH][A][HD]
  float* pbT  = agv + SZ_AG;         // [NH][A][N]
  float* qb   = pbT + SZ_PB;         // [NH][A][N]
  float* psum = qb + SZ_PB;
  float* pacc = psum + SZ_PSUM;
  float* t    = kT;                  // alias: kT dead after k_aattn

  k_bias<<<dim3(3602), dim3(256), 0, stream>>>(an, na, ahb, awb, hab, wab, pbT, qb);
  k_qkv<<<dim3(25, 9, BB), dim3(256), 0, stream>>>(x, Wqkv, bqkv, qT, kT, vCN);
  k_pool<<<dim3(BB*AG), dim3(192), 0, stream>>>(qT, agent);
  k_aattn<<<dim3(NCHUNK, NHD, BB), dim3(256), 0, stream>>>(kT, vCN, agent, pbT, psum, pacc);
  k_comb<<<dim3(1176), dim3(256), 0, stream>>>(psum, pacc, agv);
  k_qattn<<<dim3(13, NHD, BB), dim3(256), 0, stream>>>(qT, agent, agv, qb, vCN, dwcw, dwcb, t);
  k_proj<<<dim3(25, 3, BB), dim3(256), 0, stream>>>(t, projw, projb, out);
}

// Round 10
// 1121.064 us; speedup vs baseline: 1.4281x; 1.1179x over previous
//
#include <hip/hip_runtime.h>
#include <cstddef>

#define BB 32
#define CC 192
#define HH 56
#define WW 56
#define NP 3136          // 56*56
#define NHD 6
#define HD 32
#define AG 49
#define C3 576
#define SCALE 0.17677669529663687f   // 32^-0.5
#define NCHUNK 4         // grid n-chunks for agent attention (3136 = 4*784)
#define ATILE 112        // n-tile inside k_aattn (784 = 7*112)
#define EP 116           // padded LDS row (116%4==0 -> b128-aligned)

#define BCN ((size_t)BB*CC*NP)            // 19,267,584 floats
#define SZ_AG ((size_t)BB*AG*CC)          // 301,056
#define SZ_PB ((size_t)NHD*AG*NP)         // 921,984
#define SZ_PSUM ((size_t)BB*NHD*NCHUNK*AG)   // 37,632
#define SZ_PACC (SZ_PSUM*(size_t)HD)         // 1,204,224
// total ws: 3*BCN + 2*SZ_AG + 2*SZ_PB + SZ_PSUM + SZ_PACC = 61,490,688 floats
//         = 234.6 MiB (fits; 239.3 MiB passed in round 5)

// ---------------------------------------------------------------------------
// K0: positional biases (unchanged, validated).
// ---------------------------------------------------------------------------
__global__ __launch_bounds__(256) void k_bias(
    const float* __restrict__ an, const float* __restrict__ na,
    const float* __restrict__ ahb, const float* __restrict__ awb,
    const float* __restrict__ hab, const float* __restrict__ wab,
    float* __restrict__ pbT, float* __restrict__ qb) {
  int idx = blockIdx.x*256 + threadIdx.x;
  if (idx >= NHD*AG*NP) return;
  int n = idx % NP; int t = idx / NP; int a = t % AG; int h = t / AG;
  int y = n / WW, x = n % WW;
  float fy = (y + 0.5f)*0.125f - 0.5f;
  float fx = (x + 0.5f)*0.125f - 0.5f;
  float fyf = floorf(fy), fxf = floorf(fx);
  int y0 = (int)fyf, x0 = (int)fxf;
  float wy = fy - fyf, wx = fx - fxf;
  int y0c = min(6, max(0, y0)), y1c = min(6, max(0, y0+1));
  int x0c = min(6, max(0, x0)), x1c = min(6, max(0, x0+1));
  const float* p = an + (h*AG + a)*49;
  float b1 = (1.f-wy)*((1.f-wx)*p[y0c*7+x0c] + wx*p[y0c*7+x1c])
           + wy*((1.f-wx)*p[y1c*7+x0c] + wx*p[y1c*7+x1c]);
  b1 += ahb[(h*AG+a)*HH + y] + awb[(h*AG+a)*WW + x];
  pbT[((size_t)h*AG + a)*NP + n] = b1;          // [h][a][n]
  p = na + (h*AG + a)*49;
  float b2 = (1.f-wy)*((1.f-wx)*p[y0c*7+x0c] + wx*p[y0c*7+x1c])
           + wy*((1.f-wx)*p[y1c*7+x0c] + wx*p[y1c*7+x1c]);
  b2 += hab[(h*HH+y)*AG + a] + wab[(h*WW+x)*AG + a];
  qb[((size_t)(h*AG+a))*NP + n] = b2;
}

// ---------------------------------------------------------------------------
// K1: qkv = x^T @ Wqkv + b, LDS-free, 8-DEEP A-PREFETCH.
// Round-8 PMC: VALUBusy 47%, HBM 18.6% -> latency-bound (1 outstanding
// load/wave). 8 float2 rows held in regs -> 8 outstanding -> covers ~900cy.
// ---------------------------------------------------------------------------
#define QKV_PROC(KROW, AA) { \
  const float* wr = wp + (size_t)(KROW)*C3; \
  _Pragma("unroll") \
  for (int j=0;j<16;++j) { float bsv = wr[j]; \
    acc0[j] += (AA).x*bsv; acc1[j] += (AA).y*bsv; } }

__global__ __launch_bounds__(256) void k_qkv(
    const float* __restrict__ x, const float* __restrict__ Wq,
    const float* __restrict__ bq, float* __restrict__ qT,
    float* __restrict__ kT, float* __restrict__ vCN) {
  int b = blockIdx.z;
  int n0 = blockIdx.x * 128;
  int w  = __builtin_amdgcn_readfirstlane((int)(threadIdx.x >> 6));
  int lane = threadIdx.x & 63;
  int strip = blockIdx.y * 64 + w * 16;
  int n = n0 + 2*lane;
  bool act = n < NP;
  int nc = act ? n : 0;
  const float* xb = x + (size_t)b*CC*NP + nc;
  const float* wp = Wq + strip;
  float acc0[16], acc1[16];
#pragma unroll
  for (int j=0;j<16;++j) { acc0[j]=0.f; acc1[j]=0.f; }
#define XLD(K) (*(const float2*)(xb + (size_t)(K)*NP))
  float2 c0=XLD(0),c1=XLD(1),c2=XLD(2),c3=XLD(3),
         c4=XLD(4),c5=XLD(5),c6=XLD(6),c7=XLD(7);
  for (int kk=0; kk<CC-8; kk+=8) {
    float2 t0=XLD(kk+8), t1=XLD(kk+9), t2=XLD(kk+10), t3=XLD(kk+11),
           t4=XLD(kk+12), t5=XLD(kk+13), t6=XLD(kk+14), t7=XLD(kk+15);
    QKV_PROC(kk+0,c0); QKV_PROC(kk+1,c1); QKV_PROC(kk+2,c2); QKV_PROC(kk+3,c3);
    QKV_PROC(kk+4,c4); QKV_PROC(kk+5,c5); QKV_PROC(kk+6,c6); QKV_PROC(kk+7,c7);
    c0=t0; c1=t1; c2=t2; c3=t3; c4=t4; c5=t5; c6=t6; c7=t7;
  }
  QKV_PROC(CC-8,c0); QKV_PROC(CC-7,c1); QKV_PROC(CC-6,c2); QKV_PROC(CC-5,c3);
  QKV_PROC(CC-4,c4); QKV_PROC(CC-3,c5); QKV_PROC(CC-2,c6); QKV_PROC(CC-1,c7);
#undef XLD
  if (!act) return;
  int sec = strip / 192;          // 0=q 1=k 2=v
  int r = strip % 192;
  float o0[16], o1[16];
#pragma unroll
  for (int j=0;j<16;++j) {
    float bb = bq[strip + j];
    o0[j] = acc0[j] + bb;
    o1[j] = acc1[j] + bb;
  }
  if (sec < 2) {
    int h = r >> 5;
    int d0 = r & 31;
    float* outT = (sec==0 ? qT : kT);
    float* base0 = outT + (((size_t)(b*NHD + h)*NP + n)*HD + d0);
    float* base1 = base0 + HD;
#pragma unroll
    for (int g=0; g<4; ++g) {
      *(float4*)(base0 + g*4) = make_float4(o0[g*4],o0[g*4+1],o0[g*4+2],o0[g*4+3]);
      *(float4*)(base1 + g*4) = make_float4(o1[g*4],o1[g*4+1],o1[g*4+2],o1[g*4+3]);
    }
  } else {
#pragma unroll
    for (int j=0;j<16;++j) {
      float* dst = vCN + ((size_t)b*CC + r + j)*NP + n;
      *(float2*)dst = make_float2(o0[j], o1[j]);
    }
  }
}

// ---------------------------------------------------------------------------
// K2: agent pooling, float4 + 16-deep ILP (round-9 rebuild, unmeasured).
// ---------------------------------------------------------------------------
__global__ __launch_bounds__(256) void k_pool(const float* __restrict__ qT,
                                              float* __restrict__ agent) {
  __shared__ float4 red[4][48];
  int a = blockIdx.x, b = blockIdx.y;
  int w = threadIdx.x >> 6, lane = threadIdx.x & 63;
  int p1 = a / 7, p2 = a % 7;
  if (lane < 48) {
    int h = lane >> 3, d4 = lane & 7;
    const float* base = qT + ((size_t)(b*NHD + h)*NP)*HD + d4*4;
    float4 s = make_float4(0.f,0.f,0.f,0.f);
#pragma unroll
    for (int fyy=0; fyy<2; ++fyy) {
      int y = p1*8 + 2*w + fyy;
#pragma unroll
      for (int fx=0; fx<8; ++fx) {
        int nn = y*WW + p2*8 + fx;
        float4 v = *(const float4*)(base + (size_t)nn*HD);
        s.x += v.x; s.y += v.y; s.z += v.z; s.w += v.w;
      }
    }
    red[w][lane] = s;
  }
  __syncthreads();
  if (threadIdx.x < 48) {
    float4 r0 = red[0][threadIdx.x], r1 = red[1][threadIdx.x],
           r2 = red[2][threadIdx.x], r3 = red[3][threadIdx.x];
    float4 s = make_float4((r0.x+r1.x+r2.x+r3.x)*0.015625f,
                           (r0.y+r1.y+r2.y+r3.y)*0.015625f,
                           (r0.z+r1.z+r2.z+r3.z)*0.015625f,
                           (r0.w+r1.w+r2.w+r3.w)*0.015625f);
    *(float4*)&agent[((size_t)(b*AG + a))*CC + threadIdx.x*4] = s;
  }
}

// ---------------------------------------------------------------------------
// K3: agent attention, two-phase LDS-tiled (validated round 8).
// ---------------------------------------------------------------------------
__global__ __launch_bounds__(256) void k_aattn(
    const float* __restrict__ kT, const float* __restrict__ vCN,
    const float* __restrict__ agent, const float* __restrict__ pbT,
    float* __restrict__ psum, float* __restrict__ pacc) {
  __shared__ float4 smem4[2552];               // 10208 floats = 40.8 KB
  float* e_lds = (float*)smem4;                // [56][EP] (rows 49..55 unused)
  float* v_lds = e_lds + 56*EP;                // [32][EP]
  int b = blockIdx.z, h = blockIdx.y, chunk = blockIdx.x;
  int bh = b*NHD + h;
  int tid = threadIdx.x;
  int w = __builtin_amdgcn_readfirstlane(tid >> 6);
  int lane = tid & 63;
  int gn0 = chunk * (NP/NCHUNK);               // 784*chunk
  int half = w >> 1;                           // 0: a 0..24, 1: a 25..48
  int a0 = half*25, na = half ? 24 : 25;
  int n_loc_a = (w & 1)*64 + lane;             // 0..127, active if <ATILE
  int a8 = lane & 7, d8 = lane >> 3;
  float acc[7][4];
#pragma unroll
  for (int j=0;j<7;++j)
#pragma unroll
    for (int dd=0;dd<4;++dd) acc[j][dd]=0.f;
  float se_acc = 0.f;
  const float* kb = kT + (size_t)bh*NP*HD;
  const float* vb = vCN + ((size_t)b*CC + h*HD)*NP;
  for (int tile=0; tile<7; ++tile) {
    int t0 = gn0 + tile*ATILE;
#pragma unroll
    for (int jj=0; jj<14; ++jj) {
      int f = tid + 256*jj;                    // 0..3583
      int d = f / ATILE, c = f % ATILE;
      v_lds[d*EP + c] = vb[(size_t)d*NP + t0 + c];
    }
    if (n_loc_a < ATILE) {
      int n = t0 + n_loc_a;
      const float* kr = kb + (size_t)n*HD;
      float kv[HD];
#pragma unroll
      for (int d=0; d<HD; d+=4) {
        float4 t4 = *(const float4*)(kr + d);
        kv[d]=t4.x; kv[d+1]=t4.y; kv[d+2]=t4.z; kv[d+3]=t4.w;
      }
      for (int ai=0; ai<na; ++ai) {
        int a = a0 + ai;
        const float* ag = agent + ((size_t)(b*AG + a))*CC + h*HD; // uniform
        float s0=0.f,s1=0.f,s2=0.f,s3=0.f;
#pragma unroll
        for (int d=0; d<HD; d+=4) {
          s0 += ag[d]*kv[d];   s1 += ag[d+1]*kv[d+1];
          s2 += ag[d+2]*kv[d+2]; s3 += ag[d+3]*kv[d+3];
        }
        float pb = pbT[((size_t)h*AG + a)*NP + n];
        e_lds[a*EP + n_loc_a] = __expf(((s0+s1)+(s2+s3))*SCALE + pb);
      }
    }
    __syncthreads();
#pragma unroll
    for (int i=0; i<7; ++i) {
      int nq = (i*4 + w)*4;                    // quad col
      float4 v0 = *(const float4*)&v_lds[(d8 +  0)*EP + nq];
      float4 v1 = *(const float4*)&v_lds[(d8 +  8)*EP + nq];
      float4 v2 = *(const float4*)&v_lds[(d8 + 16)*EP + nq];
      float4 v3 = *(const float4*)&v_lds[(d8 + 24)*EP + nq];
#pragma unroll
      for (int j=0;j<7;++j) {
        float4 e4 = *(const float4*)&e_lds[(a8+8*j)*EP + nq];
        acc[j][0] += e4.x*v0.x + e4.y*v0.y + e4.z*v0.z + e4.w*v0.w;
        acc[j][1] += e4.x*v1.x + e4.y*v1.y + e4.z*v1.z + e4.w*v1.w;
        acc[j][2] += e4.x*v2.x + e4.y*v2.y + e4.z*v2.z + e4.w*v2.w;
        acc[j][3] += e4.x*v3.x + e4.y*v3.y + e4.z*v3.z + e4.w*v3.w;
      }
    }
    if (tid < AG) {
      const float* er = e_lds + tid*EP;
#pragma unroll
      for (int i=0; i<ATILE/4; ++i) {
        float4 ee = *(const float4*)(er + i*4);
        se_acc += ee.x + ee.y + ee.z + ee.w;
      }
    }
    __syncthreads();
  }
  float4* red = (float4*)smem4;                // 256*7 = 1792 float4 = 28 KB
#pragma unroll
  for (int j=0;j<7;++j)
    red[tid*7 + j] = make_float4(acc[j][0],acc[j][1],acc[j][2],acc[j][3]);
  __syncthreads();
  if (tid < 64) {
#pragma unroll
    for (int j=0;j<7;++j) {
      float4 r0 = red[tid*7 + j];
      float4 r1 = red[(tid+64)*7 + j];
      float4 r2 = red[(tid+128)*7 + j];
      float4 r3 = red[(tid+192)*7 + j];
      int a = (tid & 7) + 8*j;
      if (a < AG) {
        int dbase = tid >> 3;                  // d = dbase + 8*dd (strided)
        float* pp = &pacc[(((size_t)bh*NCHUNK + chunk)*AG + a)*HD];
        pp[dbase +  0] = r0.x + r1.x + r2.x + r3.x;
        pp[dbase +  8] = r0.y + r1.y + r2.y + r3.y;
        pp[dbase + 16] = r0.z + r1.z + r2.z + r3.z;
        pp[dbase + 24] = r0.w + r1.w + r2.w + r3.w;
      }
    }
  }
  if (tid < AG)
    psum[((size_t)bh*NCHUNK + chunk)*AG + tid] = se_acc;
}

// K3b: combine partial chunks -> agent_v[b][h][a][d] (unchanged).
__global__ __launch_bounds__(256) void k_comb(
    const float* __restrict__ psum, const float* __restrict__ pacc,
    float* __restrict__ agv) {
  int idx = blockIdx.x*256 + threadIdx.x;
  if (idx >= (int)(BB*NHD*AG*HD)) return;
  int d = idx & (HD-1); int rest = idx >> 5; int a = rest % AG; int bh = rest / AG;
  float se = 0.f, sa = 0.f;
  const float* pp = psum + (size_t)bh*NCHUNK*AG + a;
  const float* pa = pacc + ((size_t)bh*NCHUNK*AG + a)*HD + d;
#pragma unroll
  for (int ch=0; ch<NCHUNK; ++ch) {
    se += pp[(size_t)ch*AG];
    sa += pa[(size_t)ch*AG*HD];
  }
  agv[idx] = sa / se;
}

// ---------------------------------------------------------------------------
// K4: q attention + fused depthwise 3x3 conv (unchanged, validated).
// ---------------------------------------------------------------------------
__global__ __launch_bounds__(256) void k_qattn(
    const float* __restrict__ qT, const float* __restrict__ agent,
    const float* __restrict__ agv, const float* __restrict__ qb,
    const float* __restrict__ v, const float* __restrict__ dwcw,
    const float* __restrict__ dwcb, float* __restrict__ t) {
  int b = blockIdx.z, h = blockIdx.y;
  int n = blockIdx.x*256 + threadIdx.x;
  bool act = n < NP;
  int nc = act ? n : 0;
  float qreg[HD];
  const float* qp = qT + ((size_t)(b*NHD + h)*NP + nc)*HD;
#pragma unroll
  for (int d=0; d<HD; d+=4) {
    float4 tv = *(const float4*)(qp+d);
    qreg[d]=tv.x; qreg[d+1]=tv.y; qreg[d+2]=tv.z; qreg[d+3]=tv.w;
  }
  float acc[HD];
#pragma unroll
  for (int d=0; d<HD; ++d) acc[d]=0.f;
  float sumE=0.f;
  const float* agb = agent + (size_t)b*AG*CC + h*HD;
  const float* avb = agv + (size_t)(b*NHD + h)*AG*HD;
  const float* qbb = qb + (size_t)h*AG*NP + nc;
  for (int a=0; a<AG; ++a) {
    const float* ar = agb + (size_t)a*CC;   // wave-uniform
    float s0=0.f,s1=0.f,s2=0.f,s3=0.f;
#pragma unroll
    for (int d=0; d<HD; d+=4) {
      s0 += qreg[d]*ar[d]; s1 += qreg[d+1]*ar[d+1];
      s2 += qreg[d+2]*ar[d+2]; s3 += qreg[d+3]*ar[d+3];
    }
    float e = __expf(((s0+s1)+(s2+s3))*SCALE + qbb[(size_t)a*NP]);
    sumE += e;
    const float* vr = avb + a*HD;           // wave-uniform
#pragma unroll
    for (int d=0; d<HD; ++d) acc[d] += e*vr[d];
  }
  float inv = 1.0f / sumE;
  int y = nc / WW, x = nc % WW;
  const float* vbase = v + (size_t)b*CC*NP;
  float* tb = t + ((size_t)b*CC + h*HD)*NP + nc;
#pragma unroll 4
  for (int d=0; d<HD; ++d) {
    int c = h*HD + d;
    const float* wp9 = dwcw + c*9;          // wave-uniform
    const float* vp = vbase + (size_t)c*NP;
    float s = dwcb[c];
#pragma unroll
    for (int dy=-1; dy<=1; ++dy) {
      int yy = y+dy; if (yy < 0 || yy >= HH) continue;
#pragma unroll
      for (int dx=-1; dx<=1; ++dx) {
        int xx = x+dx; if (xx < 0 || xx >= WW) continue;
        s += wp9[(dy+1)*3 + (dx+1)] * vp[yy*WW + xx];
      }
    }
    if (act) tb[(size_t)d*NP] = acc[d]*inv + s;
  }
}

// ---------------------------------------------------------------------------
// K6: out = t^T @ proj_w + proj_b, 8-DEEP A-PREFETCH (same fix as K1).
// ---------------------------------------------------------------------------
__global__ __launch_bounds__(256) void k_proj(
    const float* __restrict__ t, const float* __restrict__ Wp,
    const float* __restrict__ bp, float* __restrict__ out) {
  int b = blockIdx.z;
  int n0 = blockIdx.x * 128;
  int w  = __builtin_amdgcn_readfirstlane((int)(threadIdx.x >> 6));
  int lane = threadIdx.x & 63;
  int strip = blockIdx.y * 64 + w * 16;
  int n = n0 + 2*lane;
  bool act = n < NP;
  int nc = act ? n : 0;
  const float* tb = t + (size_t)b*CC*NP + nc;
  const float* wp = Wp + strip;
  float acc0[16], acc1[16];
#pragma unroll
  for (int j=0;j<16;++j) { acc0[j]=0.f; acc1[j]=0.f; }
#define PROJ_PROC(KROW, AA) { \
  const float* wr = wp + (size_t)(KROW)*CC; \
  _Pragma("unroll") \
  for (int j=0;j<16;++j) { float bsv = wr[j]; \
    acc0[j] += (AA).x*bsv; acc1[j] += (AA).y*bsv; } }
#define TLD(K) (*(const float2*)(tb + (size_t)(K)*NP))
  float2 c0=TLD(0),c1=TLD(1),c2=TLD(2),c3=TLD(3),
         c4=TLD(4),c5=TLD(5),c6=TLD(6),c7=TLD(7);
  for (int kk=0; kk<CC-8; kk+=8) {
    float2 t0=TLD(kk+8), t1=TLD(kk+9), t2=TLD(kk+10), t3=TLD(kk+11),
           t4=TLD(kk+12), t5=TLD(kk+13), t6=TLD(kk+14), t7=TLD(kk+15);
    PROJ_PROC(kk+0,c0); PROJ_PROC(kk+1,c1); PROJ_PROC(kk+2,c2); PROJ_PROC(kk+3,c3);
    PROJ_PROC(kk+4,c4); PROJ_PROC(kk+5,c5); PROJ_PROC(kk+6,c6); PROJ_PROC(kk+7,c7);
    c0=t0; c1=t1; c2=t2; c3=t3; c4=t4; c5=t5; c6=t6; c7=t7;
  }
  PROJ_PROC(CC-8,c0); PROJ_PROC(CC-7,c1); PROJ_PROC(CC-6,c2); PROJ_PROC(CC-5,c3);
  PROJ_PROC(CC-4,c4); PROJ_PROC(CC-3,c5); PROJ_PROC(CC-2,c6); PROJ_PROC(CC-1,c7);
#undef TLD
  if (!act) return;
#pragma unroll
  for (int j=0;j<16;++j) {
    float bb = bp[strip + j];
    float* dst = out + ((size_t)b*CC + strip + j)*NP + n;
    *(float2*)dst = make_float2(acc0[j] + bb, acc1[j] + bb);
  }
}

// ---------------------------------------------------------------------------
extern "C" void kernel_launch(void* const* d_in, const int* in_sizes, int n_in,
                              void* d_out, int out_size, void* d_ws, size_t ws_size,
                              hipStream_t stream) {
  const float* x    = (const float*)d_in[0];
  const float* Wqkv = (const float*)d_in[1];
  const float* bqkv = (const float*)d_in[2];
  const float* projw= (const float*)d_in[3];
  const float* projb= (const float*)d_in[4];
  const float* dwcw = (const float*)d_in[5];
  const float* dwcb = (const float*)d_in[6];
  const float* an   = (const float*)d_in[7];
  const float* na   = (const float*)d_in[8];
  const float* ahb  = (const float*)d_in[9];
  const float* awb  = (const float*)d_in[10];
  const float* hab  = (const float*)d_in[11];
  const float* wab  = (const float*)d_in[12];
  float* out = (float*)d_out;

  float* w0   = (float*)d_ws;
  float* qT   = w0;                  // [B][NH][N][HD]
  float* kT   = qT + BCN;            // [B][NH][N][HD]  (reused as t after K3)
  float* vCN  = kT + BCN;            // [B][C][N]
  float* agent= vCN + BCN;           // [B][A][C]
  float* agv  = agent + SZ_AG;       // [B][NH][A][HD]
  float* pbT  = agv + SZ_AG;         // [NH][A][N]
  float* qb   = pbT + SZ_PB;         // [NH][A][N]
  float* psum = qb + SZ_PB;
  float* pacc = psum + SZ_PSUM;
  float* t    = kT;                  // alias: kT dead after k_aattn

  k_bias<<<dim3(3602), dim3(256), 0, stream>>>(an, na, ahb, awb, hab, wab, pbT, qb);
  k_qkv<<<dim3(25, 9, BB), dim3(256), 0, stream>>>(x, Wqkv, bqkv, qT, kT, vCN);
  k_pool<<<dim3(AG, BB), dim3(256), 0, stream>>>(qT, agent);
  k_aattn<<<dim3(NCHUNK, NHD, BB), dim3(256), 0, stream>>>(kT, vCN, agent, pbT, psum, pacc);
  k_comb<<<dim3(1176), dim3(256), 0, stream>>>(psum, pacc, agv);
  k_qattn<<<dim3(13, NHD, BB), dim3(256), 0, stream>>>(qT, agent, agv, qb, vCN, dwcw, dwcb, t);
  k_proj<<<dim3(25, 3, BB), dim3(256), 0, stream>>>(t, projw, projb, out);
}